// Round 7
// baseline (170.332 us; speedup 1.0000x reference)
//
#include <hip/hip_runtime.h>

#define B_ 32
#define HH 56
#define WW 56
#define C_ 96
#define E_ 4
#define M_ 384
#define F_ 96
#define P_ 3136
#define EPS 1e-3f

typedef __attribute__((ext_vector_type(8))) __bf16 bf16x8;
typedef __attribute__((ext_vector_type(8))) short short8;
typedef __attribute__((ext_vector_type(4))) float f32x4;
typedef __attribute__((ext_vector_type(2))) float f32x2;
typedef __attribute__((ext_vector_type(4))) unsigned short us4;
typedef unsigned short u16;

__device__ __forceinline__ float bf2f(u16 s) {
  union { unsigned u; float f; } c;
  c.u = ((unsigned)s) << 16;
  return c.f;
}
__device__ __forceinline__ u16 f2bf(float f) {
  union { float f; unsigned u; } c;
  c.f = f;
  unsigned u = c.u + 0x7FFFu + ((c.u >> 16) & 1u);
  return (u16)(u >> 16);
}
__device__ __forceinline__ f32x2 bfpair(unsigned u) {
  union { unsigned i; float f; } lo, hi;
  lo.i = u << 16;
  hi.i = u & 0xffff0000u;
  f32x2 r;
  r.x = lo.f;
  r.y = hi.f;
  return r;
}
__device__ __forceinline__ unsigned pkbf(float a, float b) {
  unsigned r;
  asm("v_cvt_pk_bf16_f32 %0, %1, %2" : "=v"(r) : "v"(a), "v"(b));
  return r;
}

// ---------------- x -> bf16 + per-chunk partial channel sums
__global__ __launch_bounds__(256) void k_pool_convert(
    const float* __restrict__ x, float* __restrict__ partial, u16* __restrict__ xbf) {
  int chunk = blockIdx.x, b = blockIdx.y;
  int p0 = chunk * 49;
  const float* xb = x + ((size_t)b * P_ + p0) * C_;
  u16* xo = xbf + ((size_t)b * P_ + p0) * C_;
  int t = threadIdx.x;
  int c4 = t % 24, s = t / 24;
  __shared__ f32x4 part[10][24];
  if (s < 10) {
    f32x4 sum = {0.f, 0.f, 0.f, 0.f};
    for (int p = s; p < 49; p += 10) {
      f32x4 v = *(const f32x4*)&xb[(size_t)p * C_ + c4 * 4];
      sum += v;
      us4 o;
      o.x = f2bf(v.x); o.y = f2bf(v.y); o.z = f2bf(v.z); o.w = f2bf(v.w);
      *(us4*)&xo[(size_t)p * C_ + c4 * 4] = o;
    }
    part[s][c4] = sum;
  }
  __syncthreads();
  if (s == 0) {
    f32x4 acc = part[0][c4];
#pragma unroll
    for (int ss = 1; ss < 10; ++ss) acc += part[ss][c4];
    *(f32x4*)&partial[(((size_t)b * 64 + chunk)) * C_ + c4 * 4] = acc;
  }
}

// ---------------- finish pooling + dense + sigmoid
__global__ __launch_bounds__(128) void k_routing2(
    const float* __restrict__ partial, const float* __restrict__ Wr,
    const float* __restrict__ br, float* __restrict__ rw) {
  int b = blockIdx.x;
  int c = threadIdx.x;
  __shared__ float pooled[C_];
  if (c < C_) {
    float s = 0.f;
    for (int ch = 0; ch < 64; ++ch) s += partial[((size_t)b * 64 + ch) * C_ + c];
    pooled[c] = s * (1.f / (float)P_);
  }
  __syncthreads();
  if (c < E_) {
    float acc = br[c];
    for (int cc = 0; cc < C_; ++cc) acc += pooled[cc] * Wr[cc * E_ + c];
    rw[b * E_ + c] = 1.f / (1.f + expf(-acc));
  }
}

// ---------------- all weight combines. grid (B_, 13), 256 thr
// seg 0..5 : Wk_t[b][m][c] (BN1-folded, bf16)
// seg 6    : Wdwf_t[b][m][10] (BN2-folded) + bias1p + bias3p
// seg 7..12: Wk2_t[b][f][m] (BN3-folded, bf16)
__global__ __launch_bounds__(256) void k_mkall(
    const float* __restrict__ Wpw, const float* __restrict__ bpw,
    const float* __restrict__ Wdw, const float* __restrict__ bdw,
    const float* __restrict__ Wpwl, const float* __restrict__ bpwl,
    const float* __restrict__ rw,
    const float* __restrict__ g1, const float* __restrict__ b1,
    const float* __restrict__ m1, const float* __restrict__ v1,
    const float* __restrict__ g2, const float* __restrict__ b2,
    const float* __restrict__ m2, const float* __restrict__ v2,
    const float* __restrict__ g3, const float* __restrict__ b3,
    const float* __restrict__ m3, const float* __restrict__ v3,
    u16* __restrict__ Wk_t, float* __restrict__ bias1p,
    float* __restrict__ Wdwf_t,
    u16* __restrict__ Wk2_t, float* __restrict__ bias3p) {
  int b = blockIdx.x, seg = blockIdx.y;
  float r0 = rw[b * 4 + 0], r1 = rw[b * 4 + 1], r2 = rw[b * 4 + 2], r3 = rw[b * 4 + 3];
  int t = threadIdx.x;
  if (seg < 6) {
    __shared__ __align__(16) u16 tile[64][104];
    int ml = t & 63;
    int m = seg * 64 + ml, cp = t >> 6;
    float s1 = g1[m] * rsqrtf(v1[m] + EPS);
#pragma unroll
    for (int j = 0; j < 24; ++j) {
      int c = cp + 4 * j;
      float w = r0 * Wpw[(0 * C_ + c) * M_ + m] + r1 * Wpw[(1 * C_ + c) * M_ + m] +
                r2 * Wpw[(2 * C_ + c) * M_ + m] + r3 * Wpw[(3 * C_ + c) * M_ + m];
      tile[ml][c] = f2bf(w * s1);
    }
    __syncthreads();
    u16* dst = Wk_t + ((size_t)b * M_ + seg * 64) * C_;
#pragma unroll
    for (int k = 0; k < 3; ++k) {
      int ch = t + 256 * k;
      int mr = ch / 12, off = (ch % 12) * 8;
      *(short8*)&dst[(size_t)mr * C_ + off] = *(const short8*)&tile[mr][off];
    }
  } else if (seg == 6) {
    for (int m = t; m < M_; m += 256) {
      float s2 = g2[m] * rsqrtf(v2[m] + EPS);
      float* base = Wdwf_t + ((size_t)b * M_ + m) * 10;
#pragma unroll
      for (int tap = 0; tap < 9; ++tap) {
        float w = r0 * Wdw[(0 * 9 + tap) * M_ + m] + r1 * Wdw[(1 * 9 + tap) * M_ + m] +
                  r2 * Wdw[(2 * 9 + tap) * M_ + m] + r3 * Wdw[(3 * 9 + tap) * M_ + m];
        base[tap] = w * s2;
      }
      float bias = r0 * bdw[m] + r1 * bdw[M_ + m] + r2 * bdw[2 * M_ + m] + r3 * bdw[3 * M_ + m];
      base[9] = (bias - m2[m]) * s2 + b2[m];
      float s1 = g1[m] * rsqrtf(v1[m] + EPS);
      float bb = r0 * bpw[m] + r1 * bpw[M_ + m] + r2 * bpw[2 * M_ + m] + r3 * bpw[3 * M_ + m];
      bias1p[b * M_ + m] = (bb - m1[m]) * s1 + b1[m];
    }
    if (t < F_) {
      float s3 = g3[t] * rsqrtf(v3[t] + EPS);
      float bb = r0 * bpwl[t] + r1 * bpwl[F_ + t] + r2 * bpwl[2 * F_ + t] + r3 * bpwl[3 * F_ + t];
      bias3p[b * F_ + t] = (bb - m3[t]) * s3 + b3[t];
    }
  } else {
    __shared__ __align__(16) u16 tile2[96][72];
    int m0 = (seg - 7) * 64;
#pragma unroll
    for (int j = 0; j < 24; ++j) {
      int id = t + 256 * j;
      int m = id / 96, f = id % 96;
      float w = r0 * Wpwl[(0 * M_ + m0 + m) * F_ + f] + r1 * Wpwl[(1 * M_ + m0 + m) * F_ + f] +
                r2 * Wpwl[(2 * M_ + m0 + m) * F_ + f] + r3 * Wpwl[(3 * M_ + m0 + m) * F_ + f];
      float s3 = g3[f] * rsqrtf(v3[f] + EPS);
      tile2[f][m] = f2bf(w * s3);
    }
    __syncthreads();
    u16* dst = Wk2_t + (size_t)b * F_ * M_ + m0;
#pragma unroll
    for (int k = 0; k < 3; ++k) {
      int ch = t + 256 * k;
      int f = ch / 8, off = (ch % 8) * 8;
      *(short8*)&dst[(size_t)f * M_ + off] = *(const short8*)&tile2[f][off];
    }
  }
}

// ---------------- expand GEMM -> h1 [b][m][p] (channel-major)
// wave owns 64 rows x 384 cols; barrier-free; 8B stores
__global__ __launch_bounds__(256) void k_expand(
    const u16* __restrict__ xbf, const u16* __restrict__ Wk_t,
    const float* __restrict__ bias1p, u16* __restrict__ h1) {
  int b = blockIdx.y;
  int t = threadIdx.x;
  int w = t >> 6, lane = t & 63;
  int wid = blockIdx.x * 4 + w;
  if (wid >= 49) return;
  int r15 = lane & 15, g = lane >> 4;
  int r0 = wid * 64;
  int k0 = g * 8;
  const u16* A = xbf + (size_t)b * P_ * C_;
  bf16x8 af[4][3];
#pragma unroll
  for (int fr = 0; fr < 4; ++fr)
#pragma unroll
    for (int kc = 0; kc < 3; ++kc)
      af[fr][kc] = *(const bf16x8*)&A[(size_t)(r0 + fr * 16 + r15) * C_ + kc * 32 + k0];
  const u16* Bt = Wk_t + (size_t)b * M_ * C_;
  u16* h1b = h1 + (size_t)b * M_ * P_;
  for (int nt = 0; nt < 6; ++nt) {
    f32x4 acc[4][4] = {};  // [ct][fr]
#pragma unroll
    for (int kc = 0; kc < 3; ++kc) {
#pragma unroll
      for (int ct = 0; ct < 4; ++ct) {
        bf16x8 bb = *(const bf16x8*)
            &Bt[(size_t)(nt * 64 + ct * 16 + r15) * C_ + kc * 32 + k0];
#pragma unroll
        for (int fr = 0; fr < 4; ++fr)
          acc[ct][fr] = __builtin_amdgcn_mfma_f32_16x16x32_bf16(af[fr][kc], bb, acc[ct][fr], 0, 0, 0);
      }
    }
#pragma unroll
    for (int ct = 0; ct < 4; ++ct) {
      int m = nt * 64 + ct * 16 + r15;
      float bias = bias1p[b * M_ + m];
      u16* plane = h1b + (size_t)m * P_;
#pragma unroll
      for (int fr = 0; fr < 4; ++fr) {
        int p = r0 + fr * 16 + g * 4;
        float v0 = fmaxf(acc[ct][fr][0] + bias, 0.f);
        float v1 = fmaxf(acc[ct][fr][1] + bias, 0.f);
        float v2 = fmaxf(acc[ct][fr][2] + bias, 0.f);
        float v3 = fmaxf(acc[ct][fr][3] + bias, 0.f);
        uint2 st = {pkbf(v0, v1), pkbf(v2, v3)};
        *(uint2*)&plane[p] = st;
      }
    }
  }
}

// ---------------- depthwise 3x3 + BN2 + relu
// in h1 [b][m][p]; out h2 [b][p][m] row-major
// block = (32-ch group, 14-row strip, b); LDS tile [16 y][58 x][40 (32ch+pad)]
__global__ __launch_bounds__(256) void k_dw(
    const u16* __restrict__ h1, const float* __restrict__ Wdwf,
    u16* __restrict__ h2) {
  int cg = blockIdx.x;    // 0..11
  int strip = blockIdx.y; // 0..3
  int b = blockIdx.z;
  int m0 = cg * 32, y0 = strip * 14;
  int t = threadIdx.x;
  __shared__ __align__(16) u16 inT[16 * 58 * 40];
  // zero x-halo columns (x_l = 0 and 57)
  if (t < 32) {
    int yl = t >> 1, xl = (t & 1) * 57;
    uint4 z4 = {0u, 0u, 0u, 0u};
#pragma unroll
    for (int c8 = 0; c8 < 4; ++c8)
      *(uint4*)&inT[(yl * 58 + xl) * 40 + c8 * 8] = z4;
  }
  // stage input: 32 ch x 16 rows x 56 x, contiguous 16B chunks per (c,row)
  const u16* src = h1 + (size_t)b * M_ * P_;
#pragma unroll
  for (int j = 0; j < 14; ++j) {
    int cid = t + 256 * j;  // 0..3583
    int o = cid % 7;
    int yl = (cid / 7) % 16;
    int c = cid / 112;
    int yg = y0 - 1 + yl;
    short8 v = {0, 0, 0, 0, 0, 0, 0, 0};
    if ((unsigned)yg < 56u)
      v = *(const short8*)&src[(size_t)(m0 + c) * P_ + yg * 56 + o * 8];
#pragma unroll
    for (int k = 0; k < 8; ++k)
      inT[(yl * 58 + o * 8 + k + 1) * 40 + c] = (u16)v[k];
  }
  __syncthreads();
  // thread = (channel-pair cp, p-slot pi)
  int cp = t & 15, pi = t >> 4;
  int c0 = m0 + cp * 2;
  const float* wa = Wdwf + ((size_t)b * M_ + c0) * 10;
  f32x2 wv[9], bias2;
#pragma unroll
  for (int tap = 0; tap < 9; ++tap) {
    wv[tap].x = wa[tap];
    wv[tap].y = wa[10 + tap];
  }
  bias2.x = wa[9];
  bias2.y = wa[19];
  u16* dst = h2 + (size_t)b * P_ * M_;
  for (int j = 0; j < 49; ++j) {
    int p = pi + 16 * j;  // 0..783
    int y = p / 56, x = p % 56;
    f32x2 acc = bias2;
#pragma unroll
    for (int dy = 0; dy < 3; ++dy) {
#pragma unroll
      for (int dx = 0; dx < 3; ++dx) {
        unsigned u = *(const unsigned*)&inT[((y + dy) * 58 + x + dx) * 40 + cp * 2];
        acc += bfpair(u) * wv[dy * 3 + dx];
      }
    }
    unsigned r = pkbf(fmaxf(acc.x, 0.f), fmaxf(acc.y, 0.f));
    int pg = (y0 + y) * 56 + x;
    *(unsigned*)&dst[(size_t)pg * M_ + c0] = r;
  }
}

// ---------------- project GEMM + bias + BN3(folded) + residual(bf16), fp32 out
// wave owns 64 rows x 96 cols; barrier-free
__global__ __launch_bounds__(256) void k_proj(
    const u16* __restrict__ h2, const u16* __restrict__ Wk2_t,
    const float* __restrict__ bias3p, const u16* __restrict__ xbf,
    float* __restrict__ outp) {
  int b = blockIdx.y;
  int t = threadIdx.x;
  int w = t >> 6, lane = t & 63;
  int wid = blockIdx.x * 4 + w;
  if (wid >= 49) return;
  int r15 = lane & 15, g = lane >> 4;
  int r0 = wid * 64;
  int k0 = g * 8;
  const u16* A = h2 + (size_t)b * P_ * M_;
  const u16* Bt = Wk2_t + (size_t)b * F_ * M_;
  f32x4 acc[6][4] = {};  // [ct][fr]
#pragma unroll 1
  for (int kc = 0; kc < 4; ++kc) {
    bf16x8 af[4][3];
#pragma unroll
    for (int fr = 0; fr < 4; ++fr)
#pragma unroll
      for (int ks = 0; ks < 3; ++ks)
        af[fr][ks] = *(const bf16x8*)
            &A[(size_t)(r0 + fr * 16 + r15) * M_ + kc * 96 + ks * 32 + k0];
#pragma unroll
    for (int ks = 0; ks < 3; ++ks) {
#pragma unroll
      for (int ct = 0; ct < 6; ++ct) {
        bf16x8 bb = *(const bf16x8*)
            &Bt[(size_t)(ct * 16 + r15) * M_ + kc * 96 + ks * 32 + k0];
#pragma unroll
        for (int fr = 0; fr < 4; ++fr)
          acc[ct][fr] = __builtin_amdgcn_mfma_f32_16x16x32_bf16(af[fr][ks], bb, acc[ct][fr], 0, 0, 0);
      }
    }
  }
  const u16* xr = xbf + (size_t)b * P_ * C_;
  float* op = outp + (size_t)b * P_ * F_;
#pragma unroll
  for (int ct = 0; ct < 6; ++ct) {
    int f = ct * 16 + r15;
    float bias = bias3p[b * F_ + f];
#pragma unroll
    for (int fr = 0; fr < 4; ++fr) {
#pragma unroll
      for (int i = 0; i < 4; ++i) {
        int p = r0 + fr * 16 + g * 4 + i;
        size_t idx = (size_t)p * F_ + f;
        op[idx] = acc[ct][fr][i] + bias + bf2f(xr[idx]);
      }
    }
  }
}

extern "C" void kernel_launch(void* const* d_in, const int* in_sizes, int n_in,
                              void* d_out, int out_size, void* d_ws, size_t ws_size,
                              hipStream_t stream) {
  (void)in_sizes; (void)n_in; (void)out_size; (void)ws_size;
  const float* x    = (const float*)d_in[0];
  const float* Wr   = (const float*)d_in[1];
  const float* br   = (const float*)d_in[2];
  const float* Wpw  = (const float*)d_in[3];
  const float* bpw  = (const float*)d_in[4];
  const float* Wdw  = (const float*)d_in[5];
  const float* bdw  = (const float*)d_in[6];
  const float* Wpwl = (const float*)d_in[7];
  const float* bpwl = (const float*)d_in[8];
  const float* g1 = (const float*)d_in[9];
  const float* b1 = (const float*)d_in[10];
  const float* m1 = (const float*)d_in[11];
  const float* v1 = (const float*)d_in[12];
  const float* g2 = (const float*)d_in[13];
  const float* b2 = (const float*)d_in[14];
  const float* m2 = (const float*)d_in[15];
  const float* v2 = (const float*)d_in[16];
  const float* g3 = (const float*)d_in[17];
  const float* b3 = (const float*)d_in[18];
  const float* m3 = (const float*)d_in[19];
  const float* v3 = (const float*)d_in[20];
  float* out = (float*)d_out;

  char* p = (char*)d_ws;
  auto alloc = [&](size_t bytes) {
    char* r = p;
    p += (bytes + 255) & ~(size_t)255;
    return r;
  };
  float* rw      = (float*)alloc((size_t)B_ * E_ * 4);
  float* partial = (float*)alloc((size_t)B_ * 64 * C_ * 4);
  u16*   xbf     = (u16*)  alloc((size_t)B_ * P_ * C_ * 2);
  u16*   Wk_t    = (u16*)  alloc((size_t)B_ * M_ * C_ * 2);
  float* bias1p  = (float*)alloc((size_t)B_ * M_ * 4);
  float* Wdwf_t  = (float*)alloc((size_t)B_ * M_ * 10 * 4);
  u16*   Wk2_t   = (u16*)  alloc((size_t)B_ * F_ * M_ * 2);
  float* bias3p  = (float*)alloc((size_t)B_ * F_ * 4);
  u16*   h1      = (u16*)  alloc((size_t)B_ * M_ * P_ * 2);
  u16*   h2      = (u16*)  alloc((size_t)B_ * P_ * M_ * 2);

  k_pool_convert<<<dim3(64, B_), 256, 0, stream>>>(x, partial, xbf);
  k_routing2<<<B_, 128, 0, stream>>>(partial, Wr, br, rw);
  k_mkall<<<dim3(B_, 13), 256, 0, stream>>>(Wpw, bpw, Wdw, bdw, Wpwl, bpwl, rw,
                                            g1, b1, m1, v1, g2, b2, m2, v2,
                                            g3, b3, m3, v3,
                                            Wk_t, bias1p, Wdwf_t, Wk2_t, bias3p);
  k_expand<<<dim3(13, B_), 256, 0, stream>>>(xbf, Wk_t, bias1p, h1);
  k_dw<<<dim3(12, 4, B_), 256, 0, stream>>>(h1, Wdwf_t, h2);
  k_proj<<<dim3(13, B_), 256, 0, stream>>>(h2, Wk2_t, bias3p, xbf, out);
}

// Round 8
// 156.199 us; speedup vs baseline: 1.0905x; 1.0905x over previous
//
#include <hip/hip_runtime.h>

#define B_ 32
#define HH 56
#define WW 56
#define C_ 96
#define E_ 4
#define M_ 384
#define F_ 96
#define P_ 3136
#define EPS 1e-3f

typedef __attribute__((ext_vector_type(8))) __bf16 bf16x8;
typedef __attribute__((ext_vector_type(8))) short short8;
typedef __attribute__((ext_vector_type(4))) float f32x4;
typedef __attribute__((ext_vector_type(2))) float f32x2;
typedef __attribute__((ext_vector_type(4))) unsigned short us4;
typedef unsigned short u16;

__device__ __forceinline__ float bf2f(u16 s) {
  union { unsigned u; float f; } c;
  c.u = ((unsigned)s) << 16;
  return c.f;
}
__device__ __forceinline__ u16 f2bf(float f) {
  union { float f; unsigned u; } c;
  c.f = f;
  unsigned u = c.u + 0x7FFFu + ((c.u >> 16) & 1u);
  return (u16)(u >> 16);
}
__device__ __forceinline__ unsigned pkbf(float a, float b) {
  unsigned r;
  asm("v_cvt_pk_bf16_f32 %0, %1, %2" : "=v"(r) : "v"(a), "v"(b));
  return r;
}

// ---------------- x -> bf16 + per-chunk partial channel sums
__global__ __launch_bounds__(256) void k_pool_convert(
    const float* __restrict__ x, float* __restrict__ partial, u16* __restrict__ xbf) {
  int chunk = blockIdx.x, b = blockIdx.y;
  int p0 = chunk * 49;
  const float* xb = x + ((size_t)b * P_ + p0) * C_;
  u16* xo = xbf + ((size_t)b * P_ + p0) * C_;
  int t = threadIdx.x;
  int c4 = t % 24, s = t / 24;
  __shared__ f32x4 part[10][24];
  if (s < 10) {
    f32x4 sum = {0.f, 0.f, 0.f, 0.f};
    for (int p = s; p < 49; p += 10) {
      f32x4 v = *(const f32x4*)&xb[(size_t)p * C_ + c4 * 4];
      sum += v;
      us4 o;
      o.x = f2bf(v.x); o.y = f2bf(v.y); o.z = f2bf(v.z); o.w = f2bf(v.w);
      *(us4*)&xo[(size_t)p * C_ + c4 * 4] = o;
    }
    part[s][c4] = sum;
  }
  __syncthreads();
  if (s == 0) {
    f32x4 acc = part[0][c4];
#pragma unroll
    for (int ss = 1; ss < 10; ++ss) acc += part[ss][c4];
    *(f32x4*)&partial[(((size_t)b * 64 + chunk)) * C_ + c4 * 4] = acc;
  }
}

// ---------------- finish pooling + dense + sigmoid
__global__ __launch_bounds__(128) void k_routing2(
    const float* __restrict__ partial, const float* __restrict__ Wr,
    const float* __restrict__ br, float* __restrict__ rw) {
  int b = blockIdx.x;
  int c = threadIdx.x;
  __shared__ float pooled[C_];
  if (c < C_) {
    float s = 0.f;
    for (int ch = 0; ch < 64; ++ch) s += partial[((size_t)b * 64 + ch) * C_ + c];
    pooled[c] = s * (1.f / (float)P_);
  }
  __syncthreads();
  if (c < E_) {
    float acc = br[c];
    for (int cc = 0; cc < C_; ++cc) acc += pooled[cc] * Wr[cc * E_ + c];
    rw[b * E_ + c] = 1.f / (1.f + expf(-acc));
  }
}

// ---------------- all weight combines. grid (B_, 13), 256 thr
__global__ __launch_bounds__(256) void k_mkall(
    const float* __restrict__ Wpw, const float* __restrict__ bpw,
    const float* __restrict__ Wdw, const float* __restrict__ bdw,
    const float* __restrict__ Wpwl, const float* __restrict__ bpwl,
    const float* __restrict__ rw,
    const float* __restrict__ g1, const float* __restrict__ b1,
    const float* __restrict__ m1, const float* __restrict__ v1,
    const float* __restrict__ g2, const float* __restrict__ b2,
    const float* __restrict__ m2, const float* __restrict__ v2,
    const float* __restrict__ g3, const float* __restrict__ b3,
    const float* __restrict__ m3, const float* __restrict__ v3,
    u16* __restrict__ Wk_t, float* __restrict__ bias1p,
    float* __restrict__ Wdwf_t,
    u16* __restrict__ Wk2_t, float* __restrict__ bias3p) {
  int b = blockIdx.x, seg = blockIdx.y;
  float r0 = rw[b * 4 + 0], r1 = rw[b * 4 + 1], r2 = rw[b * 4 + 2], r3 = rw[b * 4 + 3];
  int t = threadIdx.x;
  if (seg < 6) {
    __shared__ __align__(16) u16 tile[64][104];
    int ml = t & 63;
    int m = seg * 64 + ml, cp = t >> 6;
    float s1 = g1[m] * rsqrtf(v1[m] + EPS);
#pragma unroll
    for (int j = 0; j < 24; ++j) {
      int c = cp + 4 * j;
      float w = r0 * Wpw[(0 * C_ + c) * M_ + m] + r1 * Wpw[(1 * C_ + c) * M_ + m] +
                r2 * Wpw[(2 * C_ + c) * M_ + m] + r3 * Wpw[(3 * C_ + c) * M_ + m];
      tile[ml][c] = f2bf(w * s1);
    }
    __syncthreads();
    u16* dst = Wk_t + ((size_t)b * M_ + seg * 64) * C_;
#pragma unroll
    for (int k = 0; k < 3; ++k) {
      int ch = t + 256 * k;
      int mr = ch / 12, off = (ch % 12) * 8;
      *(short8*)&dst[(size_t)mr * C_ + off] = *(const short8*)&tile[mr][off];
    }
  } else if (seg == 6) {
    for (int m = t; m < M_; m += 256) {
      float s2 = g2[m] * rsqrtf(v2[m] + EPS);
      float* base = Wdwf_t + ((size_t)b * M_ + m) * 10;
#pragma unroll
      for (int tap = 0; tap < 9; ++tap) {
        float w = r0 * Wdw[(0 * 9 + tap) * M_ + m] + r1 * Wdw[(1 * 9 + tap) * M_ + m] +
                  r2 * Wdw[(2 * 9 + tap) * M_ + m] + r3 * Wdw[(3 * 9 + tap) * M_ + m];
        base[tap] = w * s2;
      }
      float bias = r0 * bdw[m] + r1 * bdw[M_ + m] + r2 * bdw[2 * M_ + m] + r3 * bdw[3 * M_ + m];
      base[9] = (bias - m2[m]) * s2 + b2[m];
      float s1 = g1[m] * rsqrtf(v1[m] + EPS);
      float bb = r0 * bpw[m] + r1 * bpw[M_ + m] + r2 * bpw[2 * M_ + m] + r3 * bpw[3 * M_ + m];
      bias1p[b * M_ + m] = (bb - m1[m]) * s1 + b1[m];
    }
    if (t < F_) {
      float s3 = g3[t] * rsqrtf(v3[t] + EPS);
      float bb = r0 * bpwl[t] + r1 * bpwl[F_ + t] + r2 * bpwl[2 * F_ + t] + r3 * bpwl[3 * F_ + t];
      bias3p[b * F_ + t] = (bb - m3[t]) * s3 + b3[t];
    }
  } else {
    __shared__ __align__(16) u16 tile2[96][72];
    int m0 = (seg - 7) * 64;
#pragma unroll
    for (int j = 0; j < 24; ++j) {
      int id = t + 256 * j;
      int m = id / 96, f = id % 96;
      float w = r0 * Wpwl[(0 * M_ + m0 + m) * F_ + f] + r1 * Wpwl[(1 * M_ + m0 + m) * F_ + f] +
                r2 * Wpwl[(2 * M_ + m0 + m) * F_ + f] + r3 * Wpwl[(3 * M_ + m0 + m) * F_ + f];
      float s3 = g3[f] * rsqrtf(v3[f] + EPS);
      tile2[f][m] = f2bf(w * s3);
    }
    __syncthreads();
    u16* dst = Wk2_t + (size_t)b * F_ * M_ + m0;
#pragma unroll
    for (int k = 0; k < 3; ++k) {
      int ch = t + 256 * k;
      int f = ch / 8, off = (ch % 8) * 8;
      *(short8*)&dst[(size_t)f * M_ + off] = *(const short8*)&tile2[f][off];
    }
  }
}

// ---------------- expand GEMM -> h1 [b][m][p] (channel-major)
// wave owns 64 rows x 384 cols; barrier-free; 8B stores
__global__ __launch_bounds__(256) void k_expand(
    const u16* __restrict__ xbf, const u16* __restrict__ Wk_t,
    const float* __restrict__ bias1p, u16* __restrict__ h1) {
  int b = blockIdx.y;
  int t = threadIdx.x;
  int w = t >> 6, lane = t & 63;
  int wid = blockIdx.x * 4 + w;
  if (wid >= 49) return;
  int r15 = lane & 15, g = lane >> 4;
  int r0 = wid * 64;
  int k0 = g * 8;
  const u16* A = xbf + (size_t)b * P_ * C_;
  bf16x8 af[4][3];
#pragma unroll
  for (int fr = 0; fr < 4; ++fr)
#pragma unroll
    for (int kc = 0; kc < 3; ++kc)
      af[fr][kc] = *(const bf16x8*)&A[(size_t)(r0 + fr * 16 + r15) * C_ + kc * 32 + k0];
  const u16* Bt = Wk_t + (size_t)b * M_ * C_;
  u16* h1b = h1 + (size_t)b * M_ * P_;
  for (int nt = 0; nt < 6; ++nt) {
    f32x4 acc[4][4] = {};  // [ct][fr]
#pragma unroll
    for (int kc = 0; kc < 3; ++kc) {
#pragma unroll
      for (int ct = 0; ct < 4; ++ct) {
        bf16x8 bb = *(const bf16x8*)
            &Bt[(size_t)(nt * 64 + ct * 16 + r15) * C_ + kc * 32 + k0];
#pragma unroll
        for (int fr = 0; fr < 4; ++fr)
          acc[ct][fr] = __builtin_amdgcn_mfma_f32_16x16x32_bf16(af[fr][kc], bb, acc[ct][fr], 0, 0, 0);
      }
    }
#pragma unroll
    for (int ct = 0; ct < 4; ++ct) {
      int m = nt * 64 + ct * 16 + r15;
      float bias = bias1p[b * M_ + m];
      u16* plane = h1b + (size_t)m * P_;
#pragma unroll
      for (int fr = 0; fr < 4; ++fr) {
        int p = r0 + fr * 16 + g * 4;
        float v0 = fmaxf(acc[ct][fr][0] + bias, 0.f);
        float v1 = fmaxf(acc[ct][fr][1] + bias, 0.f);
        float v2 = fmaxf(acc[ct][fr][2] + bias, 0.f);
        float v3 = fmaxf(acc[ct][fr][3] + bias, 0.f);
        uint2 st = {pkbf(v0, v1), pkbf(v2, v3)};
        *(uint2*)&plane[p] = st;
      }
    }
  }
}

// ---------------- depthwise 3x3 + BN2 + relu: pure plane stencil, no LDS
// h1 [b][m][p] -> h2 [b][m][p]; thread = (channel, 8-wide x chunk), 14-row strip
__global__ __launch_bounds__(256) void k_dw(
    const u16* __restrict__ h1, const float* __restrict__ Wdwf,
    u16* __restrict__ h2) {
  int mg = blockIdx.x;    // 0..11 (32 channels each)
  int strip = blockIdx.y; // 0..3
  int b = blockIdx.z;
  int t = threadIdx.x;
  if (t >= 224) return;
  int m_l = t / 7, xc = t % 7;
  int c = mg * 32 + m_l;
  int x0 = xc * 8, y0 = strip * 14;
  const u16* src = h1 + ((size_t)b * M_ + c) * P_;
  u16* dst = h2 + ((size_t)b * M_ + c) * P_;
  const float* wa = Wdwf + ((size_t)b * M_ + c) * 10;
  float wv[9];
#pragma unroll
  for (int i = 0; i < 9; ++i) wv[i] = wa[i];
  float bias = wa[9];
  float r[3][10];
  auto loadrow = [&](float* rr, int yy) {
    if ((unsigned)yy < 56u) {
      short8 v = *(const short8*)&src[yy * 56 + x0];
#pragma unroll
      for (int k = 0; k < 8; ++k) rr[k + 1] = bf2f((u16)v[k]);
      rr[0] = (x0 > 0) ? bf2f(src[yy * 56 + x0 - 1]) : 0.f;
      rr[9] = (x0 + 8 < 56) ? bf2f(src[yy * 56 + x0 + 8]) : 0.f;
    } else {
#pragma unroll
      for (int k = 0; k < 10; ++k) rr[k] = 0.f;
    }
  };
  loadrow(r[0], y0 - 1);
  loadrow(r[1], y0);
#pragma unroll
  for (int j = 0; j < 14; ++j) {
    loadrow(r[(j + 2) % 3], y0 + j + 1);
    float(&ra)[10] = r[j % 3];
    float(&rb)[10] = r[(j + 1) % 3];
    float(&rc)[10] = r[(j + 2) % 3];
    float a[8];
#pragma unroll
    for (int xx = 0; xx < 8; ++xx) {
      float acc = bias;
#pragma unroll
      for (int dx = 0; dx < 3; ++dx)
        acc += ra[xx + dx] * wv[dx] + rb[xx + dx] * wv[3 + dx] + rc[xx + dx] * wv[6 + dx];
      a[xx] = fmaxf(acc, 0.f);
    }
    uint4 st = {pkbf(a[0], a[1]), pkbf(a[2], a[3]), pkbf(a[4], a[5]), pkbf(a[6], a[7])};
    *(uint4*)&dst[(y0 + j) * 56 + x0] = st;
  }
}

// ---------------- project GEMM + bias + BN3(folded) + residual(bf16), fp32 out
// wave owns 64 p x 96 f; per-wave LDS A-staging (transpose [m][p] -> [p][m]);
// NO block barriers (wave-private LDS slice + in-order DS pipe)
__global__ __launch_bounds__(256) void k_proj(
    const u16* __restrict__ h2, const u16* __restrict__ Wk2_t,
    const float* __restrict__ bias3p, const u16* __restrict__ xbf,
    float* __restrict__ outp) {
  __shared__ __align__(16) u16 As[4][64][104];
  int b = blockIdx.y;
  int t = threadIdx.x;
  int w = t >> 6, lane = t & 63;
  int wid = blockIdx.x * 4 + w;
  if (wid >= 49) return;
  int r15 = lane & 15, g = lane >> 4;
  int r0 = wid * 64;
  int k0 = g * 8;
  const u16* A = h2 + (size_t)b * M_ * P_;
  const u16* Bt = Wk2_t + (size_t)b * F_ * M_;
  u16* asl = &As[w][0][0];
  f32x4 acc[6][4] = {};  // [ct][fr]
#pragma unroll 1
  for (int kc = 0; kc < 4; ++kc) {
    // stage 96 m x 64 p chunk, transposed to As[p][m] (channel pairs -> b32 writes)
#pragma unroll
    for (int j = 0; j < 6; ++j) {
      int idx = lane + 64 * j;  // 0..383
      int m2 = idx % 48, pch = idx / 48;
      const u16* s0 = &A[(size_t)(kc * 96 + 2 * m2) * P_ + r0 + pch * 8];
      short8 v0 = *(const short8*)s0;
      short8 v1 = *(const short8*)(s0 + P_);
#pragma unroll
      for (int i = 0; i < 8; ++i) {
        unsigned pk = ((unsigned)(unsigned short)v0[i]) |
                      (((unsigned)(unsigned short)v1[i]) << 16);
        *(unsigned*)&asl[(pch * 8 + i) * 104 + 2 * m2] = pk;
      }
    }
    asm volatile("s_waitcnt lgkmcnt(0)" ::: "memory");
    __builtin_amdgcn_sched_barrier(0);
    bf16x8 af[4][3];
#pragma unroll
    for (int fr = 0; fr < 4; ++fr)
#pragma unroll
      for (int ks = 0; ks < 3; ++ks)
        af[fr][ks] = *(const bf16x8*)&asl[(fr * 16 + r15) * 104 + ks * 32 + k0];
#pragma unroll
    for (int ks = 0; ks < 3; ++ks) {
#pragma unroll
      for (int ct = 0; ct < 6; ++ct) {
        bf16x8 bb = *(const bf16x8*)
            &Bt[(size_t)(ct * 16 + r15) * M_ + kc * 96 + ks * 32 + k0];
#pragma unroll
        for (int fr = 0; fr < 4; ++fr)
          acc[ct][fr] = __builtin_amdgcn_mfma_f32_16x16x32_bf16(af[fr][ks], bb, acc[ct][fr], 0, 0, 0);
      }
    }
  }
  const u16* xr = xbf + (size_t)b * P_ * C_;
  float* op = outp + (size_t)b * P_ * F_;
#pragma unroll
  for (int ct = 0; ct < 6; ++ct) {
    int f = ct * 16 + r15;
    float bias = bias3p[b * F_ + f];
#pragma unroll
    for (int fr = 0; fr < 4; ++fr) {
#pragma unroll
      for (int i = 0; i < 4; ++i) {
        int p = r0 + fr * 16 + g * 4 + i;
        size_t idx = (size_t)p * F_ + f;
        op[idx] = acc[ct][fr][i] + bias + bf2f(xr[idx]);
      }
    }
  }
}

extern "C" void kernel_launch(void* const* d_in, const int* in_sizes, int n_in,
                              void* d_out, int out_size, void* d_ws, size_t ws_size,
                              hipStream_t stream) {
  (void)in_sizes; (void)n_in; (void)out_size; (void)ws_size;
  const float* x    = (const float*)d_in[0];
  const float* Wr   = (const float*)d_in[1];
  const float* br   = (const float*)d_in[2];
  const float* Wpw  = (const float*)d_in[3];
  const float* bpw  = (const float*)d_in[4];
  const float* Wdw  = (const float*)d_in[5];
  const float* bdw  = (const float*)d_in[6];
  const float* Wpwl = (const float*)d_in[7];
  const float* bpwl = (const float*)d_in[8];
  const float* g1 = (const float*)d_in[9];
  const float* b1 = (const float*)d_in[10];
  const float* m1 = (const float*)d_in[11];
  const float* v1 = (const float*)d_in[12];
  const float* g2 = (const float*)d_in[13];
  const float* b2 = (const float*)d_in[14];
  const float* m2 = (const float*)d_in[15];
  const float* v2 = (const float*)d_in[16];
  const float* g3 = (const float*)d_in[17];
  const float* b3 = (const float*)d_in[18];
  const float* m3 = (const float*)d_in[19];
  const float* v3 = (const float*)d_in[20];
  float* out = (float*)d_out;

  char* p = (char*)d_ws;
  auto alloc = [&](size_t bytes) {
    char* r = p;
    p += (bytes + 255) & ~(size_t)255;
    return r;
  };
  float* rw      = (float*)alloc((size_t)B_ * E_ * 4);
  float* partial = (float*)alloc((size_t)B_ * 64 * C_ * 4);
  u16*   xbf     = (u16*)  alloc((size_t)B_ * P_ * C_ * 2);
  u16*   Wk_t    = (u16*)  alloc((size_t)B_ * M_ * C_ * 2);
  float* bias1p  = (float*)alloc((size_t)B_ * M_ * 4);
  float* Wdwf_t  = (float*)alloc((size_t)B_ * M_ * 10 * 4);
  u16*   Wk2_t   = (u16*)  alloc((size_t)B_ * F_ * M_ * 2);
  float* bias3p  = (float*)alloc((size_t)B_ * F_ * 4);
  u16*   h1      = (u16*)  alloc((size_t)B_ * M_ * P_ * 2);
  u16*   h2      = (u16*)  alloc((size_t)B_ * M_ * P_ * 2);

  k_pool_convert<<<dim3(64, B_), 256, 0, stream>>>(x, partial, xbf);
  k_routing2<<<B_, 128, 0, stream>>>(partial, Wr, br, rw);
  k_mkall<<<dim3(B_, 13), 256, 0, stream>>>(Wpw, bpw, Wdw, bdw, Wpwl, bpwl, rw,
                                            g1, b1, m1, v1, g2, b2, m2, v2,
                                            g3, b3, m3, v3,
                                            Wk_t, bias1p, Wdwf_t, Wk2_t, bias3p);
  k_expand<<<dim3(13, B_), 256, 0, stream>>>(xbf, Wk_t, bias1p, h1);
  k_dw<<<dim3(12, 4, B_), 256, 0, stream>>>(h1, Wdwf_t, h2);
  k_proj<<<dim3(13, B_), 256, 0, stream>>>(h2, Wk2_t, bias3p, xbf, out);
}

// Round 9
// 141.455 us; speedup vs baseline: 1.2041x; 1.1042x over previous
//
#include <hip/hip_runtime.h>

#define B_ 32
#define HH 56
#define WW 56
#define C_ 96
#define E_ 4
#define M_ 384
#define F_ 96
#define P_ 3136
#define EPS 1e-3f

typedef __attribute__((ext_vector_type(8))) __bf16 bf16x8;
typedef __attribute__((ext_vector_type(8))) short short8;
typedef __attribute__((ext_vector_type(4))) float f32x4;
typedef __attribute__((ext_vector_type(2))) float f32x2;
typedef __attribute__((ext_vector_type(4))) unsigned short us4;
typedef unsigned short u16;

__device__ __forceinline__ float bf2f(u16 s) {
  union { unsigned u; float f; } c;
  c.u = ((unsigned)s) << 16;
  return c.f;
}
__device__ __forceinline__ u16 f2bf(float f) {
  union { float f; unsigned u; } c;
  c.f = f;
  unsigned u = c.u + 0x7FFFu + ((c.u >> 16) & 1u);
  return (u16)(u >> 16);
}
__device__ __forceinline__ unsigned pkbf(float a, float b) {
  unsigned r;
  asm("v_cvt_pk_bf16_f32 %0, %1, %2" : "=v"(r) : "v"(a), "v"(b));
  return r;
}
__device__ __forceinline__ f32x2 mk2(float a, float b) {
  f32x2 r;
  r.x = a;
  r.y = b;
  return r;
}

// ---------------- x -> bf16 + per-chunk partial channel sums
__global__ __launch_bounds__(256) void k_pool_convert(
    const float* __restrict__ x, float* __restrict__ partial, u16* __restrict__ xbf) {
  int chunk = blockIdx.x, b = blockIdx.y;
  int p0 = chunk * 49;
  const float* xb = x + ((size_t)b * P_ + p0) * C_;
  u16* xo = xbf + ((size_t)b * P_ + p0) * C_;
  int t = threadIdx.x;
  int c4 = t % 24, s = t / 24;
  __shared__ f32x4 part[10][24];
  if (s < 10) {
    f32x4 sum = {0.f, 0.f, 0.f, 0.f};
    for (int p = s; p < 49; p += 10) {
      f32x4 v = *(const f32x4*)&xb[(size_t)p * C_ + c4 * 4];
      sum += v;
      us4 o;
      o.x = f2bf(v.x); o.y = f2bf(v.y); o.z = f2bf(v.z); o.w = f2bf(v.w);
      *(us4*)&xo[(size_t)p * C_ + c4 * 4] = o;
    }
    part[s][c4] = sum;
  }
  __syncthreads();
  if (s == 0) {
    f32x4 acc = part[0][c4];
#pragma unroll
    for (int ss = 1; ss < 10; ++ss) acc += part[ss][c4];
    *(f32x4*)&partial[(((size_t)b * 64 + chunk)) * C_ + c4 * 4] = acc;
  }
}

// ---------------- finish pooling + dense + sigmoid
__global__ __launch_bounds__(128) void k_routing2(
    const float* __restrict__ partial, const float* __restrict__ Wr,
    const float* __restrict__ br, float* __restrict__ rw) {
  int b = blockIdx.x;
  int c = threadIdx.x;
  __shared__ float pooled[C_];
  if (c < C_) {
    float s = 0.f;
    for (int ch = 0; ch < 64; ++ch) s += partial[((size_t)b * 64 + ch) * C_ + c];
    pooled[c] = s * (1.f / (float)P_);
  }
  __syncthreads();
  if (c < E_) {
    float acc = br[c];
    for (int cc = 0; cc < C_; ++cc) acc += pooled[cc] * Wr[cc * E_ + c];
    rw[b * E_ + c] = 1.f / (1.f + expf(-acc));
  }
}

// ---------------- all weight combines. grid (B_, 13), 256 thr
__global__ __launch_bounds__(256) void k_mkall(
    const float* __restrict__ Wpw, const float* __restrict__ bpw,
    const float* __restrict__ Wdw, const float* __restrict__ bdw,
    const float* __restrict__ Wpwl, const float* __restrict__ bpwl,
    const float* __restrict__ rw,
    const float* __restrict__ g1, const float* __restrict__ b1,
    const float* __restrict__ m1, const float* __restrict__ v1,
    const float* __restrict__ g2, const float* __restrict__ b2,
    const float* __restrict__ m2, const float* __restrict__ v2,
    const float* __restrict__ g3, const float* __restrict__ b3,
    const float* __restrict__ m3, const float* __restrict__ v3,
    u16* __restrict__ Wk_t, float* __restrict__ bias1p,
    float* __restrict__ Wdwf_t,
    u16* __restrict__ Wk2_t, float* __restrict__ bias3p) {
  int b = blockIdx.x, seg = blockIdx.y;
  float r0 = rw[b * 4 + 0], r1 = rw[b * 4 + 1], r2 = rw[b * 4 + 2], r3 = rw[b * 4 + 3];
  int t = threadIdx.x;
  if (seg < 6) {
    __shared__ __align__(16) u16 tile[64][104];
    int ml = t & 63;
    int m = seg * 64 + ml, cp = t >> 6;
    float s1 = g1[m] * rsqrtf(v1[m] + EPS);
#pragma unroll
    for (int j = 0; j < 24; ++j) {
      int c = cp + 4 * j;
      float w = r0 * Wpw[(0 * C_ + c) * M_ + m] + r1 * Wpw[(1 * C_ + c) * M_ + m] +
                r2 * Wpw[(2 * C_ + c) * M_ + m] + r3 * Wpw[(3 * C_ + c) * M_ + m];
      tile[ml][c] = f2bf(w * s1);
    }
    __syncthreads();
    u16* dst = Wk_t + ((size_t)b * M_ + seg * 64) * C_;
#pragma unroll
    for (int k = 0; k < 3; ++k) {
      int ch = t + 256 * k;
      int mr = ch / 12, off = (ch % 12) * 8;
      *(short8*)&dst[(size_t)mr * C_ + off] = *(const short8*)&tile[mr][off];
    }
  } else if (seg == 6) {
    for (int m = t; m < M_; m += 256) {
      float s2 = g2[m] * rsqrtf(v2[m] + EPS);
      float* base = Wdwf_t + ((size_t)b * M_ + m) * 10;
#pragma unroll
      for (int tap = 0; tap < 9; ++tap) {
        float w = r0 * Wdw[(0 * 9 + tap) * M_ + m] + r1 * Wdw[(1 * 9 + tap) * M_ + m] +
                  r2 * Wdw[(2 * 9 + tap) * M_ + m] + r3 * Wdw[(3 * 9 + tap) * M_ + m];
        base[tap] = w * s2;
      }
      float bias = r0 * bdw[m] + r1 * bdw[M_ + m] + r2 * bdw[2 * M_ + m] + r3 * bdw[3 * M_ + m];
      base[9] = (bias - m2[m]) * s2 + b2[m];
      float s1 = g1[m] * rsqrtf(v1[m] + EPS);
      float bb = r0 * bpw[m] + r1 * bpw[M_ + m] + r2 * bpw[2 * M_ + m] + r3 * bpw[3 * M_ + m];
      bias1p[b * M_ + m] = (bb - m1[m]) * s1 + b1[m];
    }
    if (t < F_) {
      float s3 = g3[t] * rsqrtf(v3[t] + EPS);
      float bb = r0 * bpwl[t] + r1 * bpwl[F_ + t] + r2 * bpwl[2 * F_ + t] + r3 * bpwl[3 * F_ + t];
      bias3p[b * F_ + t] = (bb - m3[t]) * s3 + b3[t];
    }
  } else {
    __shared__ __align__(16) u16 tile2[96][72];
    int m0 = (seg - 7) * 64;
#pragma unroll
    for (int j = 0; j < 24; ++j) {
      int id = t + 256 * j;
      int m = id / 96, f = id % 96;
      float w = r0 * Wpwl[(0 * M_ + m0 + m) * F_ + f] + r1 * Wpwl[(1 * M_ + m0 + m) * F_ + f] +
                r2 * Wpwl[(2 * M_ + m0 + m) * F_ + f] + r3 * Wpwl[(3 * M_ + m0 + m) * F_ + f];
      float s3 = g3[f] * rsqrtf(v3[f] + EPS);
      tile2[f][m] = f2bf(w * s3);
    }
    __syncthreads();
    u16* dst = Wk2_t + (size_t)b * F_ * M_ + m0;
#pragma unroll
    for (int k = 0; k < 3; ++k) {
      int ch = t + 256 * k;
      int f = ch / 8, off = (ch % 8) * 8;
      *(short8*)&dst[(size_t)f * M_ + off] = *(const short8*)&tile2[f][off];
    }
  }
}

// ---------------- expand GEMM -> h1 [b][m][p] (channel-major)
// wave owns 64 rows x 384 cols; barrier-free; 8B stores
__global__ __launch_bounds__(256) void k_expand(
    const u16* __restrict__ xbf, const u16* __restrict__ Wk_t,
    const float* __restrict__ bias1p, u16* __restrict__ h1) {
  int b = blockIdx.y;
  int t = threadIdx.x;
  int w = t >> 6, lane = t & 63;
  int wid = blockIdx.x * 4 + w;
  if (wid >= 49) return;
  int r15 = lane & 15, g = lane >> 4;
  int r0 = wid * 64;
  int k0 = g * 8;
  const u16* A = xbf + (size_t)b * P_ * C_;
  bf16x8 af[4][3];
#pragma unroll
  for (int fr = 0; fr < 4; ++fr)
#pragma unroll
    for (int kc = 0; kc < 3; ++kc)
      af[fr][kc] = *(const bf16x8*)&A[(size_t)(r0 + fr * 16 + r15) * C_ + kc * 32 + k0];
  const u16* Bt = Wk_t + (size_t)b * M_ * C_;
  u16* h1b = h1 + (size_t)b * M_ * P_;
  for (int nt = 0; nt < 6; ++nt) {
    f32x4 acc[4][4] = {};  // [ct][fr]
#pragma unroll
    for (int kc = 0; kc < 3; ++kc) {
#pragma unroll
      for (int ct = 0; ct < 4; ++ct) {
        bf16x8 bb = *(const bf16x8*)
            &Bt[(size_t)(nt * 64 + ct * 16 + r15) * C_ + kc * 32 + k0];
#pragma unroll
        for (int fr = 0; fr < 4; ++fr)
          acc[ct][fr] = __builtin_amdgcn_mfma_f32_16x16x32_bf16(af[fr][kc], bb, acc[ct][fr], 0, 0, 0);
      }
    }
#pragma unroll
    for (int ct = 0; ct < 4; ++ct) {
      int m = nt * 64 + ct * 16 + r15;
      float bias = bias1p[b * M_ + m];
      u16* plane = h1b + (size_t)m * P_;
#pragma unroll
      for (int fr = 0; fr < 4; ++fr) {
        int p = r0 + fr * 16 + g * 4;
        float v0 = fmaxf(acc[ct][fr][0] + bias, 0.f);
        float v1 = fmaxf(acc[ct][fr][1] + bias, 0.f);
        float v2 = fmaxf(acc[ct][fr][2] + bias, 0.f);
        float v3 = fmaxf(acc[ct][fr][3] + bias, 0.f);
        uint2 st = {pkbf(v0, v1), pkbf(v2, v3)};
        *(uint2*)&plane[p] = st;
      }
    }
  }
}

// ---------------- depthwise 3x3 + BN2 + relu
// in h1 [b][m][p] (plane stencil, register window, coalesced reads);
// out h2 [b][p][m] via LDS transpose tile (conflict-free u32 writes,
// 64B-per-row coalesced uint4 stores).
// block = (32-ch group, 8-row strip, b); 256 thr
__global__ __launch_bounds__(256) void k_dw(
    const u16* __restrict__ h1, const float* __restrict__ Wdwf,
    u16* __restrict__ h2) {
  int cg = blockIdx.x;    // 0..11
  int strip = blockIdx.y; // 0..6
  int b = blockIdx.z;
  int m0 = cg * 32, y0 = strip * 8;
  int t = threadIdx.x;
  __shared__ __align__(16) u16 ot[448][40];  // [p_local][32ch + 8 pad]

  if (t < 224) {
    int rh = t / 112;       // row-half: 4 rows each
    int rem = t % 112;
    int cp = rem / 7, xc = rem % 7;
    int c0 = m0 + cp * 2;
    int x0 = xc * 8;
    const u16* s0 = h1 + ((size_t)b * M_ + c0) * P_;
    const u16* s1 = s0 + P_;
    const float* wa = Wdwf + ((size_t)b * M_ + c0) * 10;
    f32x2 wv[9], bias2;
#pragma unroll
    for (int tap = 0; tap < 9; ++tap) wv[tap] = mk2(wa[tap], wa[10 + tap]);
    bias2 = mk2(wa[9], wa[19]);
    f32x2 r[3][10];
    auto loadrow = [&](f32x2* rr, int yy) {
      if ((unsigned)yy < 56u) {
        short8 v0 = *(const short8*)&s0[yy * 56 + x0];
        short8 v1 = *(const short8*)&s1[yy * 56 + x0];
#pragma unroll
        for (int k = 0; k < 8; ++k)
          rr[k + 1] = mk2(bf2f((u16)v0[k]), bf2f((u16)v1[k]));
        rr[0] = (x0 > 0) ? mk2(bf2f(s0[yy * 56 + x0 - 1]), bf2f(s1[yy * 56 + x0 - 1]))
                         : mk2(0.f, 0.f);
        rr[9] = (x0 + 8 < 56) ? mk2(bf2f(s0[yy * 56 + x0 + 8]), bf2f(s1[yy * 56 + x0 + 8]))
                              : mk2(0.f, 0.f);
      } else {
#pragma unroll
        for (int k = 0; k < 10; ++k) rr[k] = mk2(0.f, 0.f);
      }
    };
    int yb = y0 + rh * 4;
    loadrow(r[0], yb - 1);
    loadrow(r[1], yb);
#pragma unroll
    for (int j = 0; j < 4; ++j) {
      loadrow(r[(j + 2) % 3], yb + j + 1);
      f32x2(&ra)[10] = r[j % 3];
      f32x2(&rb)[10] = r[(j + 1) % 3];
      f32x2(&rc)[10] = r[(j + 2) % 3];
#pragma unroll
      for (int xx = 0; xx < 8; ++xx) {
        f32x2 acc = bias2;
#pragma unroll
        for (int dx = 0; dx < 3; ++dx)
          acc += ra[xx + dx] * wv[dx] + rb[xx + dx] * wv[3 + dx] + rc[xx + dx] * wv[6 + dx];
        unsigned pk = pkbf(fmaxf(acc.x, 0.f), fmaxf(acc.y, 0.f));
        int p_l = (rh * 4 + j) * 56 + x0 + xx;
        *(unsigned*)&ot[p_l][cp * 2] = pk;
      }
    }
  }
  __syncthreads();
  // write out [p][m]: 64B contiguous per p row (4 lanes x 16B)
  int p_l0 = t >> 2, q = t & 3;
  u16* dst = h2 + (size_t)b * P_ * M_ + (size_t)(y0 * 56) * M_ + m0 + q * 8;
#pragma unroll
  for (int pass = 0; pass < 7; ++pass) {
    int pl = p_l0 + pass * 64;
    uint4 v = *(const uint4*)&ot[pl][q * 8];
    *(uint4*)&dst[(size_t)pl * M_] = v;
  }
}

// ---------------- project GEMM + bias + BN3(folded) + residual(bf16), fp32 out
// classic block-cooperative As/Bs staging, 2 barriers/kc (proven R3 structure)
__global__ __launch_bounds__(256) void k_proj(
    const u16* __restrict__ h2, const u16* __restrict__ Wk2_t,
    const float* __restrict__ bias3p, const u16* __restrict__ xbf,
    float* __restrict__ outp) {
  __shared__ __align__(16) u16 As[64][104];
  __shared__ __align__(16) u16 Bs[96][104];
  int pt = blockIdx.x, b = blockIdx.y;
  int p0 = pt * 64;
  int t = threadIdx.x;
  const u16* A = h2 + ((size_t)b * P_ + p0) * M_;
  const u16* Bt = Wk2_t + (size_t)b * F_ * M_;
  int lane = t & 63, w = t >> 6;
  int rA = w * 16 + (lane & 15);
  int k0 = (lane >> 4) * 8;
  f32x4 acc[6] = {};
  for (int kc = 0; kc < 4; ++kc) {
    if (kc) __syncthreads();
#pragma unroll
    for (int j = 0; j < 3; ++j) {
      int ch = t + 256 * j;
      int r = ch / 12, o = (ch % 12) * 8;
      *(short8*)&As[r][o] = *(const short8*)&A[(size_t)r * M_ + kc * 96 + o];
    }
#pragma unroll
    for (int j = 0; j < 5; ++j) {
      int ch = t + 256 * j;
      if (ch < 96 * 12) {
        int r = ch / 12, o = (ch % 12) * 8;
        *(short8*)&Bs[r][o] = *(const short8*)&Bt[(size_t)r * M_ + kc * 96 + o];
      }
    }
    __syncthreads();
#pragma unroll
    for (int ks = 0; ks < 3; ++ks) {
      bf16x8 a = *(const bf16x8*)&As[rA][ks * 32 + k0];
#pragma unroll
      for (int ct = 0; ct < 6; ++ct) {
        bf16x8 bb = *(const bf16x8*)&Bs[ct * 16 + (lane & 15)][ks * 32 + k0];
        acc[ct] = __builtin_amdgcn_mfma_f32_16x16x32_bf16(a, bb, acc[ct], 0, 0, 0);
      }
    }
  }
  const u16* xr = xbf + (size_t)b * P_ * C_;
  float* op = outp + (size_t)b * P_ * F_;
  int rowb = p0 + w * 16 + (lane >> 4) * 4;
#pragma unroll
  for (int ct = 0; ct < 6; ++ct) {
    int f = ct * 16 + (lane & 15);
    float bias = bias3p[b * F_ + f];
#pragma unroll
    for (int i = 0; i < 4; ++i) {
      size_t idx = (size_t)(rowb + i) * F_ + f;
      op[idx] = acc[ct][i] + bias + bf2f(xr[idx]);
    }
  }
}

extern "C" void kernel_launch(void* const* d_in, const int* in_sizes, int n_in,
                              void* d_out, int out_size, void* d_ws, size_t ws_size,
                              hipStream_t stream) {
  (void)in_sizes; (void)n_in; (void)out_size; (void)ws_size;
  const float* x    = (const float*)d_in[0];
  const float* Wr   = (const float*)d_in[1];
  const float* br   = (const float*)d_in[2];
  const float* Wpw  = (const float*)d_in[3];
  const float* bpw  = (const float*)d_in[4];
  const float* Wdw  = (const float*)d_in[5];
  const float* bdw  = (const float*)d_in[6];
  const float* Wpwl = (const float*)d_in[7];
  const float* bpwl = (const float*)d_in[8];
  const float* g1 = (const float*)d_in[9];
  const float* b1 = (const float*)d_in[10];
  const float* m1 = (const float*)d_in[11];
  const float* v1 = (const float*)d_in[12];
  const float* g2 = (const float*)d_in[13];
  const float* b2 = (const float*)d_in[14];
  const float* m2 = (const float*)d_in[15];
  const float* v2 = (const float*)d_in[16];
  const float* g3 = (const float*)d_in[17];
  const float* b3 = (const float*)d_in[18];
  const float* m3 = (const float*)d_in[19];
  const float* v3 = (const float*)d_in[20];
  float* out = (float*)d_out;

  char* p = (char*)d_ws;
  auto alloc = [&](size_t bytes) {
    char* r = p;
    p += (bytes + 255) & ~(size_t)255;
    return r;
  };
  float* rw      = (float*)alloc((size_t)B_ * E_ * 4);
  float* partial = (float*)alloc((size_t)B_ * 64 * C_ * 4);
  u16*   xbf     = (u16*)  alloc((size_t)B_ * P_ * C_ * 2);
  u16*   Wk_t    = (u16*)  alloc((size_t)B_ * M_ * C_ * 2);
  float* bias1p  = (float*)alloc((size_t)B_ * M_ * 4);
  float* Wdwf_t  = (float*)alloc((size_t)B_ * M_ * 10 * 4);
  u16*   Wk2_t   = (u16*)  alloc((size_t)B_ * F_ * M_ * 2);
  float* bias3p  = (float*)alloc((size_t)B_ * F_ * 4);
  u16*   h1      = (u16*)  alloc((size_t)B_ * M_ * P_ * 2);
  u16*   h2      = (u16*)  alloc((size_t)B_ * P_ * M_ * 2);

  k_pool_convert<<<dim3(64, B_), 256, 0, stream>>>(x, partial, xbf);
  k_routing2<<<B_, 128, 0, stream>>>(partial, Wr, br, rw);
  k_mkall<<<dim3(B_, 13), 256, 0, stream>>>(Wpw, bpw, Wdw, bdw, Wpwl, bpwl, rw,
                                            g1, b1, m1, v1, g2, b2, m2, v2,
                                            g3, b3, m3, v3,
                                            Wk_t, bias1p, Wdwf_t, Wk2_t, bias3p);
  k_expand<<<dim3(13, B_), 256, 0, stream>>>(xbf, Wk_t, bias1p, h1);
  k_dw<<<dim3(12, 7, B_), 256, 0, stream>>>(h1, Wdwf_t, h2);
  k_proj<<<dim3(49, B_), 256, 0, stream>>>(h2, Wk2_t, bias3p, xbf, out);
}

// Round 10
// 137.562 us; speedup vs baseline: 1.2382x; 1.0283x over previous
//
#include <hip/hip_runtime.h>

#define B_ 32
#define HH 56
#define WW 56
#define C_ 96
#define E_ 4
#define M_ 384
#define F_ 96
#define P_ 3136
#define EPS 1e-3f

typedef __attribute__((ext_vector_type(8))) __bf16 bf16x8;
typedef __attribute__((ext_vector_type(8))) short short8;
typedef __attribute__((ext_vector_type(4))) float f32x4;
typedef __attribute__((ext_vector_type(2))) float f32x2;
typedef __attribute__((ext_vector_type(4))) unsigned short us4;
typedef unsigned short u16;

__device__ __forceinline__ float bf2f(u16 s) {
  union { unsigned u; float f; } c;
  c.u = ((unsigned)s) << 16;
  return c.f;
}
__device__ __forceinline__ u16 f2bf(float f) {
  union { float f; unsigned u; } c;
  c.f = f;
  unsigned u = c.u + 0x7FFFu + ((c.u >> 16) & 1u);
  return (u16)(u >> 16);
}
__device__ __forceinline__ unsigned pkbf(float a, float b) {
  unsigned r;
  asm("v_cvt_pk_bf16_f32 %0, %1, %2" : "=v"(r) : "v"(a), "v"(b));
  return r;
}
__device__ __forceinline__ f32x2 mk2(float a, float b) {
  f32x2 r;
  r.x = a;
  r.y = b;
  return r;
}

// ---------------- x -> bf16 + per-chunk partial channel sums
__global__ __launch_bounds__(256) void k_pool_convert(
    const float* __restrict__ x, float* __restrict__ partial, u16* __restrict__ xbf) {
  int chunk = blockIdx.x, b = blockIdx.y;
  int p0 = chunk * 49;
  const float* xb = x + ((size_t)b * P_ + p0) * C_;
  u16* xo = xbf + ((size_t)b * P_ + p0) * C_;
  int t = threadIdx.x;
  int c4 = t % 24, s = t / 24;
  __shared__ f32x4 part[10][24];
  if (s < 10) {
    f32x4 sum = {0.f, 0.f, 0.f, 0.f};
    for (int p = s; p < 49; p += 10) {
      f32x4 v = *(const f32x4*)&xb[(size_t)p * C_ + c4 * 4];
      sum += v;
      us4 o;
      o.x = f2bf(v.x); o.y = f2bf(v.y); o.z = f2bf(v.z); o.w = f2bf(v.w);
      *(us4*)&xo[(size_t)p * C_ + c4 * 4] = o;
    }
    part[s][c4] = sum;
  }
  __syncthreads();
  if (s == 0) {
    f32x4 acc = part[0][c4];
#pragma unroll
    for (int ss = 1; ss < 10; ++ss) acc += part[ss][c4];
    *(f32x4*)&partial[(((size_t)b * 64 + chunk)) * C_ + c4 * 4] = acc;
  }
}

// ---------------- all weight combines (+ routing fused). grid (B_, 13), 256 thr
__global__ __launch_bounds__(256) void k_mkall(
    const float* __restrict__ partial, const float* __restrict__ Wr,
    const float* __restrict__ br,
    const float* __restrict__ Wpw, const float* __restrict__ bpw,
    const float* __restrict__ Wdw, const float* __restrict__ bdw,
    const float* __restrict__ Wpwl, const float* __restrict__ bpwl,
    const float* __restrict__ g1, const float* __restrict__ b1,
    const float* __restrict__ m1, const float* __restrict__ v1,
    const float* __restrict__ g2, const float* __restrict__ b2,
    const float* __restrict__ m2, const float* __restrict__ v2,
    const float* __restrict__ g3, const float* __restrict__ b3,
    const float* __restrict__ m3, const float* __restrict__ v3,
    u16* __restrict__ Wk_t, float* __restrict__ bias1p,
    float* __restrict__ Wdwf_t,
    u16* __restrict__ Wk2_t, float* __restrict__ bias3p) {
  int b = blockIdx.x, seg = blockIdx.y;
  int t = threadIdx.x;
  // routing per block (cheap, removes a kernel launch)
  __shared__ float pooled[C_];
  __shared__ float rws[E_];
  if (t < C_) {
    float s = 0.f;
#pragma unroll 8
    for (int ch = 0; ch < 64; ++ch) s += partial[((size_t)b * 64 + ch) * C_ + t];
    pooled[t] = s * (1.f / (float)P_);
  }
  __syncthreads();
  if (t < E_) {
    float acc = br[t];
    for (int cc = 0; cc < C_; ++cc) acc += pooled[cc] * Wr[cc * E_ + t];
    rws[t] = 1.f / (1.f + expf(-acc));
  }
  __syncthreads();
  float r0 = rws[0], r1 = rws[1], r2 = rws[2], r3 = rws[3];

  if (seg < 6) {
    __shared__ __align__(16) u16 tile[64][104];
    int ml = t & 63;
    int m = seg * 64 + ml, cp = t >> 6;
    float s1 = g1[m] * rsqrtf(v1[m] + EPS);
#pragma unroll
    for (int j = 0; j < 24; ++j) {
      int c = cp + 4 * j;
      float w = r0 * Wpw[(0 * C_ + c) * M_ + m] + r1 * Wpw[(1 * C_ + c) * M_ + m] +
                r2 * Wpw[(2 * C_ + c) * M_ + m] + r3 * Wpw[(3 * C_ + c) * M_ + m];
      tile[ml][c] = f2bf(w * s1);
    }
    __syncthreads();
    u16* dst = Wk_t + ((size_t)b * M_ + seg * 64) * C_;
#pragma unroll
    for (int k = 0; k < 3; ++k) {
      int ch = t + 256 * k;
      int mr = ch / 12, off = (ch % 12) * 8;
      *(short8*)&dst[(size_t)mr * C_ + off] = *(const short8*)&tile[mr][off];
    }
  } else if (seg == 6) {
    for (int m = t; m < M_; m += 256) {
      float s2 = g2[m] * rsqrtf(v2[m] + EPS);
      float* base = Wdwf_t + ((size_t)b * M_ + m) * 10;
#pragma unroll
      for (int tap = 0; tap < 9; ++tap) {
        float w = r0 * Wdw[(0 * 9 + tap) * M_ + m] + r1 * Wdw[(1 * 9 + tap) * M_ + m] +
                  r2 * Wdw[(2 * 9 + tap) * M_ + m] + r3 * Wdw[(3 * 9 + tap) * M_ + m];
        base[tap] = w * s2;
      }
      float bias = r0 * bdw[m] + r1 * bdw[M_ + m] + r2 * bdw[2 * M_ + m] + r3 * bdw[3 * M_ + m];
      base[9] = (bias - m2[m]) * s2 + b2[m];
      float s1 = g1[m] * rsqrtf(v1[m] + EPS);
      float bb = r0 * bpw[m] + r1 * bpw[M_ + m] + r2 * bpw[2 * M_ + m] + r3 * bpw[3 * M_ + m];
      bias1p[b * M_ + m] = (bb - m1[m]) * s1 + b1[m];
    }
    if (t < F_) {
      float s3 = g3[t] * rsqrtf(v3[t] + EPS);
      float bb = r0 * bpwl[t] + r1 * bpwl[F_ + t] + r2 * bpwl[2 * F_ + t] + r3 * bpwl[3 * F_ + t];
      bias3p[b * F_ + t] = (bb - m3[t]) * s3 + b3[t];
    }
  } else {
    __shared__ __align__(16) u16 tile2[96][72];
    int m0 = (seg - 7) * 64;
#pragma unroll
    for (int j = 0; j < 24; ++j) {
      int id = t + 256 * j;
      int m = id / 96, f = id % 96;
      float w = r0 * Wpwl[(0 * M_ + m0 + m) * F_ + f] + r1 * Wpwl[(1 * M_ + m0 + m) * F_ + f] +
                r2 * Wpwl[(2 * M_ + m0 + m) * F_ + f] + r3 * Wpwl[(3 * M_ + m0 + m) * F_ + f];
      float s3 = g3[f] * rsqrtf(v3[f] + EPS);
      tile2[f][m] = f2bf(w * s3);
    }
    __syncthreads();
    u16* dst = Wk2_t + (size_t)b * F_ * M_ + m0;
#pragma unroll
    for (int k = 0; k < 3; ++k) {
      int ch = t + 256 * k;
      int f = ch / 8, off = (ch % 8) * 8;
      *(short8*)&dst[(size_t)f * M_ + off] = *(const short8*)&tile2[f][off];
    }
  }
}

// ---------------- expand GEMM -> h1 [b][m][p] (channel-major)
// wave owns 64 rows x 384 cols; barrier-free; 8B stores
__global__ __launch_bounds__(256) void k_expand(
    const u16* __restrict__ xbf, const u16* __restrict__ Wk_t,
    const float* __restrict__ bias1p, u16* __restrict__ h1) {
  int b = blockIdx.y;
  int t = threadIdx.x;
  int w = t >> 6, lane = t & 63;
  int wid = blockIdx.x * 4 + w;
  if (wid >= 49) return;
  int r15 = lane & 15, g = lane >> 4;
  int r0 = wid * 64;
  int k0 = g * 8;
  const u16* A = xbf + (size_t)b * P_ * C_;
  bf16x8 af[4][3];
#pragma unroll
  for (int fr = 0; fr < 4; ++fr)
#pragma unroll
    for (int kc = 0; kc < 3; ++kc)
      af[fr][kc] = *(const bf16x8*)&A[(size_t)(r0 + fr * 16 + r15) * C_ + kc * 32 + k0];
  const u16* Bt = Wk_t + (size_t)b * M_ * C_;
  u16* h1b = h1 + (size_t)b * M_ * P_;
  for (int nt = 0; nt < 6; ++nt) {
    f32x4 acc[4][4] = {};  // [ct][fr]
#pragma unroll
    for (int kc = 0; kc < 3; ++kc) {
#pragma unroll
      for (int ct = 0; ct < 4; ++ct) {
        bf16x8 bb = *(const bf16x8*)
            &Bt[(size_t)(nt * 64 + ct * 16 + r15) * C_ + kc * 32 + k0];
#pragma unroll
        for (int fr = 0; fr < 4; ++fr)
          acc[ct][fr] = __builtin_amdgcn_mfma_f32_16x16x32_bf16(af[fr][kc], bb, acc[ct][fr], 0, 0, 0);
      }
    }
#pragma unroll
    for (int ct = 0; ct < 4; ++ct) {
      int m = nt * 64 + ct * 16 + r15;
      float bias = bias1p[b * M_ + m];
      u16* plane = h1b + (size_t)m * P_;
#pragma unroll
      for (int fr = 0; fr < 4; ++fr) {
        int p = r0 + fr * 16 + g * 4;
        float v0 = fmaxf(acc[ct][fr][0] + bias, 0.f);
        float v1 = fmaxf(acc[ct][fr][1] + bias, 0.f);
        float v2 = fmaxf(acc[ct][fr][2] + bias, 0.f);
        float v3 = fmaxf(acc[ct][fr][3] + bias, 0.f);
        uint2 st = {pkbf(v0, v1), pkbf(v2, v3)};
        *(uint2*)&plane[p] = st;
      }
    }
  }
}

// ---------------- depthwise 3x3 + BN2 + relu
// in h1 [b][m][p] (plane stencil, register window, coalesced reads);
// out h2 [b][p][m] via LDS transpose tile, row stride 42 u16 (21 u32):
//   21*8 = 168 = 8 (mod 32) -> xc-groups spread across banks (<=2-3 way).
// Read-back as 4x ds_read_b32 (42-u16 rows are not 16B aligned).
__global__ __launch_bounds__(256) void k_dw(
    const u16* __restrict__ h1, const float* __restrict__ Wdwf,
    u16* __restrict__ h2) {
  int cg = blockIdx.x;    // 0..11
  int strip = blockIdx.y; // 0..6
  int b = blockIdx.z;
  int m0 = cg * 32, y0 = strip * 8;
  int t = threadIdx.x;
  __shared__ u16 ot[448][42];  // [p_local][32ch + 10 pad]

  if (t < 224) {
    int rh = t / 112;       // row-half: 4 rows each
    int rem = t % 112;
    int cp = rem / 7, xc = rem % 7;
    int c0 = m0 + cp * 2;
    int x0 = xc * 8;
    const u16* s0 = h1 + ((size_t)b * M_ + c0) * P_;
    const u16* s1 = s0 + P_;
    const float* wa = Wdwf + ((size_t)b * M_ + c0) * 10;
    f32x2 wv[9], bias2;
#pragma unroll
    for (int tap = 0; tap < 9; ++tap) wv[tap] = mk2(wa[tap], wa[10 + tap]);
    bias2 = mk2(wa[9], wa[19]);
    f32x2 r[3][10];
    auto loadrow = [&](f32x2* rr, int yy) {
      if ((unsigned)yy < 56u) {
        short8 v0 = *(const short8*)&s0[yy * 56 + x0];
        short8 v1 = *(const short8*)&s1[yy * 56 + x0];
#pragma unroll
        for (int k = 0; k < 8; ++k)
          rr[k + 1] = mk2(bf2f((u16)v0[k]), bf2f((u16)v1[k]));
        rr[0] = (x0 > 0) ? mk2(bf2f(s0[yy * 56 + x0 - 1]), bf2f(s1[yy * 56 + x0 - 1]))
                         : mk2(0.f, 0.f);
        rr[9] = (x0 + 8 < 56) ? mk2(bf2f(s0[yy * 56 + x0 + 8]), bf2f(s1[yy * 56 + x0 + 8]))
                              : mk2(0.f, 0.f);
      } else {
#pragma unroll
        for (int k = 0; k < 10; ++k) rr[k] = mk2(0.f, 0.f);
      }
    };
    int yb = y0 + rh * 4;
    loadrow(r[0], yb - 1);
    loadrow(r[1], yb);
#pragma unroll
    for (int j = 0; j < 4; ++j) {
      loadrow(r[(j + 2) % 3], yb + j + 1);
      f32x2(&ra)[10] = r[j % 3];
      f32x2(&rb)[10] = r[(j + 1) % 3];
      f32x2(&rc)[10] = r[(j + 2) % 3];
#pragma unroll
      for (int xx = 0; xx < 8; ++xx) {
        f32x2 acc = bias2;
#pragma unroll
        for (int dx = 0; dx < 3; ++dx)
          acc += ra[xx + dx] * wv[dx] + rb[xx + dx] * wv[3 + dx] + rc[xx + dx] * wv[6 + dx];
        unsigned pk = pkbf(fmaxf(acc.x, 0.f), fmaxf(acc.y, 0.f));
        int p_l = (rh * 4 + j) * 56 + x0 + xx;
        *(unsigned*)&ot[p_l][cp * 2] = pk;
      }
    }
  }
  __syncthreads();
  // write out [p][m]: 64B contiguous per p row (4 lanes x 16B)
  int p_l0 = t >> 2, q = t & 3;
  u16* dst = h2 + (size_t)b * P_ * M_ + (size_t)(y0 * 56) * M_ + m0 + q * 8;
#pragma unroll
  for (int pass = 0; pass < 7; ++pass) {
    int pl = p_l0 + pass * 64;
    uint4 v;
    v.x = *(const unsigned*)&ot[pl][q * 8 + 0];
    v.y = *(const unsigned*)&ot[pl][q * 8 + 2];
    v.z = *(const unsigned*)&ot[pl][q * 8 + 4];
    v.w = *(const unsigned*)&ot[pl][q * 8 + 6];
    *(uint4*)&dst[(size_t)pl * M_] = v;
  }
}

// ---------------- project GEMM + bias + BN3(folded) + residual(bf16), fp32 out
// classic block-cooperative As/Bs staging, 2 barriers/kc
__global__ __launch_bounds__(256) void k_proj(
    const u16* __restrict__ h2, const u16* __restrict__ Wk2_t,
    const float* __restrict__ bias3p, const u16* __restrict__ xbf,
    float* __restrict__ outp) {
  __shared__ __align__(16) u16 As[64][104];
  __shared__ __align__(16) u16 Bs[96][104];
  int pt = blockIdx.x, b = blockIdx.y;
  int p0 = pt * 64;
  int t = threadIdx.x;
  const u16* A = h2 + ((size_t)b * P_ + p0) * M_;
  const u16* Bt = Wk2_t + (size_t)b * F_ * M_;
  int lane = t & 63, w = t >> 6;
  int rA = w * 16 + (lane & 15);
  int k0 = (lane >> 4) * 8;
  f32x4 acc[6] = {};
  for (int kc = 0; kc < 4; ++kc) {
    if (kc) __syncthreads();
#pragma unroll
    for (int j = 0; j < 3; ++j) {
      int ch = t + 256 * j;
      int r = ch / 12, o = (ch % 12) * 8;
      *(short8*)&As[r][o] = *(const short8*)&A[(size_t)r * M_ + kc * 96 + o];
    }
#pragma unroll
    for (int j = 0; j < 5; ++j) {
      int ch = t + 256 * j;
      if (ch < 96 * 12) {
        int r = ch / 12, o = (ch % 12) * 8;
        *(short8*)&Bs[r][o] = *(const short8*)&Bt[(size_t)r * M_ + kc * 96 + o];
      }
    }
    __syncthreads();
#pragma unroll
    for (int ks = 0; ks < 3; ++ks) {
      bf16x8 a = *(const bf16x8*)&As[rA][ks * 32 + k0];
#pragma unroll
      for (int ct = 0; ct < 6; ++ct) {
        bf16x8 bb = *(const bf16x8*)&Bs[ct * 16 + (lane & 15)][ks * 32 + k0];
        acc[ct] = __builtin_amdgcn_mfma_f32_16x16x32_bf16(a, bb, acc[ct], 0, 0, 0);
      }
    }
  }
  const u16* xr = xbf + (size_t)b * P_ * C_;
  float* op = outp + (size_t)b * P_ * F_;
  int rowb = p0 + w * 16 + (lane >> 4) * 4;
#pragma unroll
  for (int ct = 0; ct < 6; ++ct) {
    int f = ct * 16 + (lane & 15);
    float bias = bias3p[b * F_ + f];
#pragma unroll
    for (int i = 0; i < 4; ++i) {
      size_t idx = (size_t)(rowb + i) * F_ + f;
      op[idx] = acc[ct][i] + bias + bf2f(xr[idx]);
    }
  }
}

extern "C" void kernel_launch(void* const* d_in, const int* in_sizes, int n_in,
                              void* d_out, int out_size, void* d_ws, size_t ws_size,
                              hipStream_t stream) {
  (void)in_sizes; (void)n_in; (void)out_size; (void)ws_size;
  const float* x    = (const float*)d_in[0];
  const float* Wr   = (const float*)d_in[1];
  const float* br   = (const float*)d_in[2];
  const float* Wpw  = (const float*)d_in[3];
  const float* bpw  = (const float*)d_in[4];
  const float* Wdw  = (const float*)d_in[5];
  const float* bdw  = (const float*)d_in[6];
  const float* Wpwl = (const float*)d_in[7];
  const float* bpwl = (const float*)d_in[8];
  const float* g1 = (const float*)d_in[9];
  const float* b1 = (const float*)d_in[10];
  const float* m1 = (const float*)d_in[11];
  const float* v1 = (const float*)d_in[12];
  const float* g2 = (const float*)d_in[13];
  const float* b2 = (const float*)d_in[14];
  const float* m2 = (const float*)d_in[15];
  const float* v2 = (const float*)d_in[16];
  const float* g3 = (const float*)d_in[17];
  const float* b3 = (const float*)d_in[18];
  const float* m3 = (const float*)d_in[19];
  const float* v3 = (const float*)d_in[20];
  float* out = (float*)d_out;

  char* p = (char*)d_ws;
  auto alloc = [&](size_t bytes) {
    char* r = p;
    p += (bytes + 255) & ~(size_t)255;
    return r;
  };
  float* partial = (float*)alloc((size_t)B_ * 64 * C_ * 4);
  u16*   xbf     = (u16*)  alloc((size_t)B_ * P_ * C_ * 2);
  u16*   Wk_t    = (u16*)  alloc((size_t)B_ * M_ * C_ * 2);
  float* bias1p  = (float*)alloc((size_t)B_ * M_ * 4);
  float* Wdwf_t  = (float*)alloc((size_t)B_ * M_ * 10 * 4);
  u16*   Wk2_t   = (u16*)  alloc((size_t)B_ * F_ * M_ * 2);
  float* bias3p  = (float*)alloc((size_t)B_ * F_ * 4);
  u16*   h1      = (u16*)  alloc((size_t)B_ * M_ * P_ * 2);
  u16*   h2      = (u16*)  alloc((size_t)B_ * P_ * M_ * 2);

  k_pool_convert<<<dim3(64, B_), 256, 0, stream>>>(x, partial, xbf);
  k_mkall<<<dim3(B_, 13), 256, 0, stream>>>(partial, Wr, br,
                                            Wpw, bpw, Wdw, bdw, Wpwl, bpwl,
                                            g1, b1, m1, v1, g2, b2, m2, v2,
                                            g3, b3, m3, v3,
                                            Wk_t, bias1p, Wdwf_t, Wk2_t, bias3p);
  k_expand<<<dim3(13, B_), 256, 0, stream>>>(xbf, Wk_t, bias1p, h1);
  k_dw<<<dim3(12, 7, B_), 256, 0, stream>>>(h1, Wdwf_t, h2);
  k_proj<<<dim3(49, B_), 256, 0, stream>>>(h2, Wk2_t, bias3p, xbf, out);
}